// Round 13
// baseline (233.984 us; speedup 1.0000x reference)
//
#include <hip/hip_runtime.h>
#include <hip/hip_bf16.h>
#include <stdint.h>

typedef __bf16 bf16;
typedef __bf16 bf16x8 __attribute__((ext_vector_type(8)));
typedef __bf16 bf16x4 __attribute__((ext_vector_type(4)));
typedef float  f32x4  __attribute__((ext_vector_type(4)));
typedef float  f32x16 __attribute__((ext_vector_type(16)));

#define S_LEN  2048
#define NH     16
#define DKV    64
#define DMODEL 1024
#define LOG2E  1.4426950408889634f

// ---------------------------------------------------------------------------
// async global->LDS 16B copy. LDS dest is wave-uniform base + lane*16.
// ---------------------------------------------------------------------------
__device__ __forceinline__ void async_load16(const void* g, void* l) {
  __builtin_amdgcn_global_load_lds(
      (const __attribute__((address_space(1))) uint32_t*)(uintptr_t)g,
      (__attribute__((address_space(3))) uint32_t*)(uintptr_t)l,
      16, 0, 0);
}

// ---------------------------------------------------------------------------
// Transpose-cast W [K=1024][N=1024] fp32 -> Wt bf16 [N][K]. grid (32,32,4), block (32,8)
// ---------------------------------------------------------------------------
__global__ void transpose_w(const float* __restrict__ W0, const float* __restrict__ W1,
                            const float* __restrict__ W2, const float* __restrict__ W3,
                            bf16* __restrict__ T0, bf16* __restrict__ T1,
                            bf16* __restrict__ T2, bf16* __restrict__ T3)
{
  int z = blockIdx.z;
  const float* W = (z == 0) ? W0 : (z == 1) ? W1 : (z == 2) ? W2 : W3;
  bf16* T = (z == 0) ? T0 : (z == 1) ? T1 : (z == 2) ? T2 : T3;
  __shared__ float tile[32][33];
  int n0 = blockIdx.x * 32, k0 = blockIdx.y * 32;
  int tx = threadIdx.x, ty = threadIdx.y;
  for (int i = 0; i < 32; i += 8)
    tile[ty + i][tx] = W[(size_t)(k0 + ty + i) * DMODEL + n0 + tx];
  __syncthreads();
  for (int i = 0; i < 32; i += 8)
    T[(size_t)(n0 + ty + i) * DMODEL + k0 + tx] = (bf16)tile[tx][ty + i];
}

// ---------------------------------------------------------------------------
// QKV GEMM v3: SINGLE-BARRIER double-buffered K-loop. Per iter k:
//   dmaB(k+1)->buf^1; cvtA(k+1)->buf^1 (regs from iter k-1); loadA(k+2);
//   MFMA(buf); barrier.  B(k+1)'s DMA stays in flight through the whole MFMA
// phase (drained at the barrier AFTER it) instead of being drained ~20 insts
// after issue as in the 2-barrier loop. cvtA's vmcnt wait targets the older
// A loads only, leaving the fresh B DMAs outstanding.
// 64x128 tile, BK=64. LDS 48KB -> 3 blocks/CU. grid (m=64, n=8, z=3); XCD=m%8.
// z<2: C bf16 head layout [B,NH,S,DKV] via LDS-restaged b128 stores.
// z==2: V in PV-permuted layout [bh][s/64][(s%64)/4][d][s%4].
// ---------------------------------------------------------------------------
__global__ __launch_bounds__(256) void gemm_qkv(
    const float* __restrict__ Aq, const float* __restrict__ Ak, const float* __restrict__ Av,
    const bf16* __restrict__ Bq, const bf16* __restrict__ Bk, const bf16* __restrict__ Bv,
    bf16* __restrict__ Cq, bf16* __restrict__ Ck, bf16* __restrict__ Cv)
{
  __shared__ __align__(16) char smem[49152];   // As dbuf 2x8K + Bs dbuf 2x16K
  bf16* As0 = (bf16*)smem;                     // [p][64*64]
  bf16* Bs0 = (bf16*)smem + 2 * 64 * 64;       // [p][128*64]
  bf16* Ls  = (bf16*)smem;                     // epilogue overlay [64][132]

  const int z = blockIdx.z;
  const float* A = (z == 0) ? Aq : (z == 1) ? Ak : Av;
  const bf16* Bt = (z == 0) ? Bq : (z == 1) ? Bk : Bv;
  bf16* C        = (z == 0) ? Cq : (z == 1) ? Ck : Cv;

  const int m0 = blockIdx.x * 64;        // m on x: XCD-local A reuse
  const int n0 = blockIdx.y * 128;
  const int tid = threadIdx.x;
  const int lane = tid & 63;
  const int wave = tid >> 6;
  const int wm = (wave >> 1) * 32;
  const int wn = (wave & 1) * 64;
  const int row = lane & 15;
  const int quad = lane >> 4;

  f32x4 acc[2][4];
  for (int i = 0; i < 2; ++i)
    for (int j = 0; j < 4; ++j) acc[i][j] = (f32x4){0.f, 0.f, 0.f, 0.f};

  // A staging: r = tid>>3 (8-lane phases share a row -> conflict-free),
  // c = tid&7; 32B fp32 -> 16B bf16 chunk, XOR-swizzled store.
  const int arc = tid & 7;
  const int arr = tid >> 3;              // 0..31; u adds 32
  const float* A0p = A + (size_t)(m0 + arr) * DMODEL + arc * 8;
  const float* A1p = A + (size_t)(m0 + 32 + arr) * DMODEL + arc * 8;

  f32x4 av0[2], av1[2];
  #define LOAD_A(kt) {                                   \
    const int kn_ = (kt) << 6;                           \
    av0[0] = *(const f32x4*)(A0p + kn_);                 \
    av1[0] = *(const f32x4*)(A0p + kn_ + 4);             \
    av0[1] = *(const f32x4*)(A1p + kn_);                 \
    av1[1] = *(const f32x4*)(A1p + kn_ + 4);             \
  }
  #define CVT_A(p) {                                     \
    bf16* Ab_ = As0 + (p) * 4096;                        \
    for (int u = 0; u < 2; ++u) {                        \
      bf16x8 o;                                          \
      for (int w = 0; w < 4; ++w) { o[w] = (bf16)av0[u][w]; o[w + 4] = (bf16)av1[u][w]; } \
      int r_ = u * 32 + arr;                             \
      *(bf16x8*)(Ab_ + r_ * 64 + ((arc ^ (r_ & 7)) << 3)) = o; \
    }                                                    \
  }
  #define DMA_B(kt, p) {                                 \
    const int kk_ = (kt) << 6;                           \
    for (int j = 0; j < 4; ++j) {                        \
      int base_ = j * 256 + wave * 64;                   \
      int idx_ = base_ + lane;                           \
      int r_ = idx_ >> 3;                                \
      int cc_ = (idx_ & 7) ^ (r_ & 7);                   \
      async_load16(Bt + (size_t)(n0 + r_) * DMODEL + kk_ + cc_ * 8, \
                   (char*)(Bs0 + (p) * 8192) + (size_t)base_ * 16); \
    }                                                    \
  }

  // prologue: stage buffers for kt=0, preload A(1)
  LOAD_A(0);
  DMA_B(0, 0);
  CVT_A(0);
  LOAD_A(1);
  __syncthreads();

  for (int kt = 0; kt < 16; ++kt) {
    const int p = kt & 1;
    if (kt < 15) { DMA_B(kt + 1, p ^ 1); CVT_A(p ^ 1); }
    if (kt < 14) LOAD_A(kt + 2);
    const bf16* Ab = As0 + p * 4096;
    const bf16* Bb = Bs0 + p * 8192;
    for (int ks = 0; ks < 2; ++ks) {
      bf16x8 af[2], bfr[4];
      for (int i = 0; i < 2; ++i) {
        int rr = wm + i * 16 + row;
        af[i] = *(const bf16x8*)(Ab + rr * 64 + (((quad + ks * 4) ^ (rr & 7)) << 3));
      }
      for (int j = 0; j < 4; ++j) {
        int rr = wn + j * 16 + row;
        bfr[j] = *(const bf16x8*)(Bb + rr * 64 + (((quad + ks * 4) ^ (rr & 7)) << 3));
      }
      for (int i = 0; i < 2; ++i)
        for (int j = 0; j < 4; ++j)
          acc[i][j] = __builtin_amdgcn_mfma_f32_16x16x32_bf16(af[i], bfr[j], acc[i][j], 0, 0, 0);
    }
    __syncthreads();                     // ONE barrier/iter; drains B(k+1) DMA
  }                                      // only after the MFMA phase above

  if (z != 2) {
    // LDS-restaged coalesced epilogue -> [B,NH,S,DKV], single pass (64 rows)
    const int bq = m0 >> 11;
    for (int i = 0; i < 2; ++i)
      for (int j = 0; j < 4; ++j)
        for (int r = 0; r < 4; ++r)
          Ls[(wm + i * 16 + quad * 4 + r) * 132 + wn + j * 16 + row] = (bf16)acc[i][j][r];
    __syncthreads();
    for (int u = 0; u < 4; ++u) {
      int cc = u * 256 + tid;             // 1024 chunks of 16B
      int rloc = cc >> 4, c8 = (cc & 15) * 8;
      int s = (m0 + rloc) & 2047;
      int gn = n0 + c8;
      int h = gn >> 6, d = gn & 63;
      bf16x8 val = *(const bf16x8*)(Ls + rloc * 132 + c8);
      *(bf16x8*)(C + (((size_t)(bq * NH + h)) * S_LEN + s) * DKV + d) = val;
    }
  } else {
    // V permuted for attn PV: [bh][tile=s/64][kb=(s%64)/4][d][sr=s%4]
    for (int i = 0; i < 2; ++i)
      for (int j = 0; j < 4; ++j) {
        int gm = m0 + wm + i * 16 + quad * 4;    // s base (r=0..3 consecutive)
        int gn = n0 + wn + j * 16 + row;
        int b = gm >> 11, s = gm & 2047;
        int h = gn >> 6,  d = gn & 63;
        int bh = b * NH + h;
        int tile = s >> 6, kb = (s & 63) >> 2;
        bf16x4 t;
        for (int r = 0; r < 4; ++r) t[r] = (bf16)acc[i][j][r];
        *(bf16x4*)(C + ((((size_t)bh * 32 + tile) * 16 + kb) * 64 + d) * 4) = t;
      }
  }
  #undef LOAD_A
  #undef CVT_A
  #undef DMA_B
}

// ---------------------------------------------------------------------------
// Flash attention: S^T = K*Q^T via 32x32x16 MFMA; P stays in registers.
// KV-split via blockIdx.z; partial O BF16 + fp32 row-sums.
// grid (bh=32, q=16, zh=2): XCD = bh%8 -> each bh's K/V served from one L2.
// ---------------------------------------------------------------------------
__global__ __launch_bounds__(256, 4) void attn_kernel(
    const bf16* __restrict__ Qh, const bf16* __restrict__ Kh, const bf16* __restrict__ Vperm,
    const float* __restrict__ mask, bf16* __restrict__ Opart, float* __restrict__ Lpart)
{
  __shared__ __align__(16) bf16 Ks[64 * 64];    // [kv][d], chunk XOR-swizzled
  __shared__ __align__(16) bf16 Vts[64 * 64];   // [kb][d][4] linear (permuted)
  __shared__ __align__(16) float masks2[64];

  const int bh = blockIdx.x;                    // bh on x: XCD-local K/V reuse
  const int b = bh >> 4;
  const int q0 = blockIdx.y * 128;
  const int zh = blockIdx.z;                    // kv half
  const int tid = threadIdx.x;
  const int lane = tid & 63;
  const int wave = tid >> 6;
  const int ln = lane & 31;
  const int hi = lane >> 5;
  const float SC2 = 0.125f * LOG2E;

  // hoisted Q B-frags: B[k=d][n=q] = Q[q][d], d = c*16 + hi*8 + u
  const int qg = q0 + wave * 32 + ln;
  bf16x8 qf[4];
  {
    const bf16* qrow = Qh + ((size_t)bh * S_LEN + qg) * DKV;
    for (int c = 0; c < 4; ++c)
      qf[c] = *(const bf16x8*)(qrow + c * 16 + hi * 8);
  }

  f32x16 O[2];
  for (int nb = 0; nb < 2; ++nb)
    for (int i = 0; i < 16; ++i) O[nb][i] = 0.f;
  float lsum = 0.f;

  for (int it = 0; it < 16; ++it) {
    const int kv0 = zh * 1024 + it * 64;
    __syncthreads();  // protect Ks/Vts/masks2 from previous iteration's readers
    const bf16* vtile = Vperm + ((size_t)bh * 32 + (kv0 >> 6)) * 4096;
    for (int j = 0; j < 2; ++j) {
      int base = j * 256 + wave * 64;       // wave-uniform
      int idx = base + lane;
      int r = idx >> 3;
      int cc = (idx & 7) ^ (r & 7);
      async_load16(Kh + ((size_t)bh * S_LEN + kv0 + r) * DKV + cc * 8,
                   (char*)Ks + (size_t)base * 16);
      async_load16(vtile + (size_t)idx * 8,
                   (char*)Vts + (size_t)base * 16);
    }
    if (tid < 64) masks2[tid] = mask[b * S_LEN + kv0 + tid] * LOG2E;
    __syncthreads();

    // S^T = K * Q^T  (A = K[kv][d], m=kv: 2 m-blocks; B = qf; 4 k-chunks)
    f32x16 Sm[2];
    for (int i = 0; i < 16; ++i) { Sm[0][i] = 0.f; Sm[1][i] = 0.f; }
    for (int c = 0; c < 4; ++c) {
      bf16x8 k0 = *(const bf16x8*)(Ks + ln * 64        + (((2 * c + hi) ^ (ln & 7)) << 3));
      bf16x8 k1 = *(const bf16x8*)(Ks + (32 + ln) * 64 + (((2 * c + hi) ^ (ln & 7)) << 3));
      Sm[0] = __builtin_amdgcn_mfma_f32_32x32x16_bf16(k0, qf[c], Sm[0], 0, 0, 0);
      Sm[1] = __builtin_amdgcn_mfma_f32_32x32x16_bf16(k1, qf[c], Sm[1], 0, 0, 0);
    }

    // P = exp2(S*SC2 + mask*LOG2E) in registers -> PV
    for (int cg = 0; cg < 4; ++cg) {
      int mb = cg >> 1, g = cg & 1;
      int koff = 32 * mb + 16 * g + 4 * hi;
      f32x4 mklo = *(const f32x4*)(masks2 + koff);
      f32x4 mkhi = *(const f32x4*)(masks2 + koff + 8);
      bf16x8 ap;
      float ls0 = 0.f;
      for (int u = 0; u < 4; ++u) {
        float p = __builtin_amdgcn_exp2f(Sm[mb][g * 8 + u] * SC2 + mklo[u]);
        ls0 += p; ap[u] = (bf16)p;
      }
      for (int u = 0; u < 4; ++u) {
        float p = __builtin_amdgcn_exp2f(Sm[mb][g * 8 + 4 + u] * SC2 + mkhi[u]);
        ls0 += p; ap[4 + u] = (bf16)p;
      }
      lsum += ls0;
      int kb0 = hi + 4 * g + 8 * mb;
      for (int nb = 0; nb < 2; ++nb) {
        int d = nb * 32 + ln;
        bf16x4 lo = *(const bf16x4*)(Vts + ((size_t)kb0 * 64 + d) * 4);
        bf16x4 hv = *(const bf16x4*)(Vts + ((size_t)(kb0 + 2) * 64 + d) * 4);
        bf16x8 bv;
        for (int u = 0; u < 4; ++u) { bv[u] = lo[u]; bv[u + 4] = hv[u]; }
        O[nb] = __builtin_amdgcn_mfma_f32_32x32x16_bf16(ap, bv, O[nb], 0, 0, 0);
      }
    }
  }

  // partial row sums
  float lt = lsum + __shfl_xor(lsum, 32, 64);
  if (lane < 32)
    Lpart[((size_t)zh * 32 + bh) * S_LEN + q0 + wave * 32 + ln] = lt;

  // partial O (un-normalized, bf16): Opart[zh][bh][q][d]
  bf16* ob = Opart + (((size_t)zh * 32 + bh) * S_LEN) * DKV;
  for (int g = 0; g < 4; ++g)
    for (int nb = 0; nb < 2; ++nb)
      for (int j = 0; j < 4; ++j) {
        int qrow = q0 + wave * 32 + j + 8 * g + 4 * hi;
        ob[(size_t)qrow * DKV + nb * 32 + ln] = (bf16)O[nb][g * 4 + j];
      }
}

// ---------------------------------------------------------------------------
// Out-GEMM v3: single-barrier dbuf pipeline; fused combine+normalize on A.
// 32x128 tile, BK=64 (kt == head). LDS 42KB -> 3 blocks/CU.
// grid (m=128, n=8) = 1024 blocks; XCD = m%8 (Opart rows L2-local).
// ---------------------------------------------------------------------------
__global__ __launch_bounds__(256) void gemm_out(
    const bf16* __restrict__ Opart, const float* __restrict__ Lpart,
    const bf16* __restrict__ Wot, float* __restrict__ Cout)
{
  __shared__ __align__(16) bf16 As0[2][32 * 64];   // 8KB dbuf, swizzled
  __shared__ __align__(16) bf16 Bs0[2][128 * 64];  // 32KB dbuf, swizzled
  __shared__ float rinv[NH * 32];                  // 2KB

  const int m0 = blockIdx.x * 32;        // m on x: XCD-local Opart reuse
  const int n0 = blockIdx.y * 128;
  const int tid = threadIdx.x;
  const int lane = tid & 63;
  const int wave = tid >> 6;
  const int wm = (wave >> 1) * 16;
  const int wn = (wave & 1) * 64;
  const int row = lane & 15;
  const int quad = lane >> 4;
  const int b = m0 >> 11;
  const int s0 = m0 & 2047;

  // per-block row-sum reciprocals for all heads x 32 rows
  for (int u = 0; u < 2; ++u) {
    int idx = u * 256 + tid;
    int h = idx >> 5, r = idx & 31;
    float l = Lpart[((size_t)(b * NH + h)) * S_LEN + s0 + r]
            + Lpart[((size_t)(32 + b * NH + h)) * S_LEN + s0 + r];
    rinv[idx] = 1.0f / l;
  }
  __syncthreads();                       // rinv visible to all (cross-thread)

  f32x4 acc[4];
  for (int j = 0; j < 4; ++j) acc[j] = (f32x4){0.f, 0.f, 0.f, 0.f};

  const int arc = tid & 7;               // chunk col
  const int arr = tid >> 3;              // row 0..31
  const bf16* O0p = Opart + ((size_t)(b * NH) * S_LEN + s0 + arr) * DKV + arc * 8;
  const bf16* O1p = Opart + ((size_t)(32 + b * NH) * S_LEN + s0 + arr) * DKV + arc * 8;
  const size_t HSTEP = (size_t)S_LEN * DKV;

  bf16x8 h0, h1;
  #define LOAD_O(kt) {                                   \
    h0 = *(const bf16x8*)(O0p + (size_t)(kt) * HSTEP);   \
    h1 = *(const bf16x8*)(O1p + (size_t)(kt) * HSTEP);   \
  }
  #define CVT_O(kt, p) {                                 \
    float rv_ = rinv[(kt) * 32 + arr];                   \
    bf16x8 o_;                                           \
    for (int w = 0; w < 8; ++w)                          \
      o_[w] = (bf16)(((float)h0[w] + (float)h1[w]) * rv_); \
    *(bf16x8*)(&As0[p][0] + arr * 64 + ((arc ^ (arr & 7)) << 3)) = o_; \
  }
  #define DMA_W(kt, p) {                                 \
    for (int j = 0; j < 4; ++j) {                        \
      int base_ = j * 256 + wave * 64;                   \
      int idx_ = base_ + lane;                           \
      int r_ = idx_ >> 3;                                \
      int cc_ = (idx_ & 7) ^ (r_ & 7);                   \
      async_load16(Wot + (size_t)(n0 + r_) * DMODEL + (kt) * 64 + cc_ * 8, \
                   (char*)(&Bs0[p][0]) + (size_t)base_ * 16); \
    }                                                    \
  }

  LOAD_O(0);
  DMA_W(0, 0);
  CVT_O(0, 0);
  LOAD_O(1);
  __syncthreads();

  for (int kt = 0; kt < 16; ++kt) {      // kt == head index (BK=64 == DKV)
    const int p = kt & 1;
    if (kt < 15) { DMA_W(kt + 1, p ^ 1); CVT_O(kt + 1, p ^ 1); }
    if (kt < 14) LOAD_O(kt + 2);
    const bf16* Ab = &As0[p][0];
    const bf16* Bb = &Bs0[p][0];
    for (int ks = 0; ks < 2; ++ks) {
      bf16x8 af, bfr[4];
      {
        int rr = wm + row;
        af = *(const bf16x8*)(Ab + rr * 64 + (((quad + ks * 4) ^ (rr & 7)) << 3));
      }
      for (int j = 0; j < 4; ++j) {
        int rr = wn + j * 16 + row;
        bfr[j] = *(const bf16x8*)(Bb + rr * 64 + (((quad + ks * 4) ^ (rr & 7)) << 3));
      }
      for (int j = 0; j < 4; ++j)
        acc[j] = __builtin_amdgcn_mfma_f32_16x16x32_bf16(af, bfr[j], acc[j], 0, 0, 0);
    }
    __syncthreads();                     // ONE barrier/iter
  }

  for (int j = 0; j < 4; ++j)
    for (int r = 0; r < 4; ++r) {
      int gm = m0 + wm + quad * 4 + r;
      int gn = n0 + wn + j * 16 + row;
      Cout[(size_t)gm * DMODEL + gn] = acc[j][r];
    }
  #undef LOAD_O
  #undef CVT_O
  #undef DMA_W
}

// ---------------------------------------------------------------------------
extern "C" void kernel_launch(void* const* d_in, const int* in_sizes, int n_in,
                              void* d_out, int out_size, void* d_ws, size_t ws_size,
                              hipStream_t stream)
{
  const float* query = (const float*)d_in[0];
  const float* key_  = (const float*)d_in[1];
  const float* value = (const float*)d_in[2];
  const float* mask  = (const float*)d_in[3];
  const float* Wq = (const float*)d_in[4];
  const float* Wk = (const float*)d_in[5];
  const float* Wv = (const float*)d_in[6];
  const float* Wo = (const float*)d_in[7];

  char* ws = (char*)d_ws;
  const size_t MB = (size_t)1 << 20;
  bf16* qh    = (bf16*)(ws + 0 * MB);    // 8MB [B,NH,S,DKV]
  bf16* kh    = (bf16*)(ws + 8 * MB);    // 8MB [B,NH,S,DKV]
  bf16* vperm = (bf16*)(ws + 16 * MB);   // 8MB PV-permuted V
  bf16* wot   = (bf16*)(ws + 24 * MB);   // 2MB (live until out-GEMM)
  bf16* Opart = (bf16*)(ws + 26 * MB);   // 16MB bf16 partials (26..42)
  bf16* wqt   = (bf16*)(ws + 26 * MB);   // 2MB each, dead after QKV GEMM
  bf16* wkt   = (bf16*)(ws + 28 * MB);   //   (overlaid by Opart afterwards)
  bf16* wvt   = (bf16*)(ws + 30 * MB);
  float* Lpart = (float*)(ws + 58 * MB); // 512KB row-sum partials

  transpose_w<<<dim3(32, 32, 4), dim3(32, 8), 0, stream>>>(Wq, Wk, Wv, Wo, wqt, wkt, wvt, wot);
  gemm_qkv<<<dim3(64, 8, 3), 256, 0, stream>>>(query, key_, value, wqt, wkt, wvt,
                                               qh, kh, vperm);
  attn_kernel<<<dim3(32, 16, 2), 256, 0, stream>>>(qh, kh, vperm, mask, Opart, Lpart);
  gemm_out<<<dim3(128, 8), 256, 0, stream>>>(Opart, Lpart, wot, (float*)d_out);
}